// Round 1
// baseline (108.810 us; speedup 1.0000x reference)
//
#include <hip/hip_runtime.h>

// PeriodicEmbedding: out[b, n*64+o] = relu( sum_i emb[b,n,i] * W[n,i,o] + bias[n,o] )
//   emb[b,n,i] = sin(2*pi*coef[n,i]*x[b,n])        for i in [0,32)
//              = cos(2*pi*coef[n,i-32]*x[b,n])     for i in [32,64)
// B=8192, N=256, D=64, H=32. Output f32 [8192, 16384] = 512 MB -> HBM-write-bound.
// Strategy: bf16 MFMA (16x16x32), A-fragments computed in registers via v_sin/v_cos
// (hardware sin takes revolutions: sin(2*pi*t) = v_sin_f32(fract(t))).

typedef short bf16x8 __attribute__((ext_vector_type(8)));
typedef float f32x4 __attribute__((ext_vector_type(4)));

#define BM   128            // rows per block (4 waves x 32 rows)
#define LDW  72             // LDS row stride for Wt (64 + 8 pad) in bf16 elems -> 144 B

__device__ __forceinline__ short f2bf(float f) {
    unsigned u = __float_as_uint(f);
    unsigned r = (u + 0x7FFFu + ((u >> 16) & 1u)) >> 16;   // RNE
    return (short)r;
}

__global__ __launch_bounds__(256) void pe_mfma_kernel(
    const float* __restrict__ x,     // [B, N]
    const float* __restrict__ coef,  // [N, 32]
    const float* __restrict__ wgt,   // [N, 64, 64]  (i, o)
    const float* __restrict__ bias,  // [N, 64]
    float* __restrict__ out)         // [B, N*64]
{
    const int N = 256;

    const int bid = blockIdx.x;
    const int n   = bid & (N - 1);        // token fastest -> L2 reuse of x lines
    const int b0  = (bid >> 8) * BM;

    __shared__ short wt[64 * LDW];        // Wt[o][i] bf16, padded rows

    const int t = threadIdx.x;

    // ---- stage W[n] transposed to LDS as bf16 ----
    const float* Wn = wgt + n * 4096;
    #pragma unroll
    for (int it = 0; it < 16; ++it) {
        int idx = it * 256 + t;           // coalesced f32 read
        int i = idx >> 6, o = idx & 63;
        wt[o * LDW + i] = f2bf(Wn[idx]);
    }
    __syncthreads();

    const int w  = t >> 6;
    const int l  = t & 63;
    const int lr = l & 15;                // lane row / col index
    const int lg = l >> 4;                // lane k-group

    // ---- coef slice for this lane's k slots (broadcast across 16 lanes) ----
    const float* cp = coef + n * 32 + lg * 8;
    float c[8];
    #pragma unroll
    for (int j = 0; j < 8; ++j) c[j] = cp[j];

    // ---- x values for this lane's two row-fragments ----
    const int row0 = b0 + w * 32 + lr;
    const float x0 = x[row0 * N + n];
    const float x1 = x[(row0 + 16) * N + n];

    // ---- A fragments in registers: sin half (k 0..31), cos half (k 32..63) ----
    bf16x8 a_s[2], a_c[2];
    #pragma unroll
    for (int m = 0; m < 2; ++m) {
        float xv = m ? x1 : x0;
        #pragma unroll
        for (int j = 0; j < 8; ++j) {
            float tt = c[j] * xv;
            tt = __builtin_amdgcn_fractf(tt);          // range-reduce (period 1 rev)
            a_s[m][j] = f2bf(__builtin_amdgcn_sinf(tt));
            a_c[m][j] = f2bf(__builtin_amdgcn_cosf(tt));
        }
    }

    // ---- B fragments from LDS (ds_read_b128, padded stride -> ~2-way conflicts) ----
    bf16x8 bfr[4][2];
    #pragma unroll
    for (int nf = 0; nf < 4; ++nf) {
        int col = nf * 16 + lr;
        #pragma unroll
        for (int ki = 0; ki < 2; ++ki) {
            int k = ki * 32 + lg * 8;
            bfr[nf][ki] = *(const bf16x8*)(&wt[col * LDW + k]);
        }
    }

    // ---- MFMA: acc[m][nf] += A_sin x B(k<32) + A_cos x B(k>=32) ----
    f32x4 acc[2][4];
    #pragma unroll
    for (int m = 0; m < 2; ++m)
        #pragma unroll
        for (int nf = 0; nf < 4; ++nf) {
            f32x4 z = {0.f, 0.f, 0.f, 0.f};
            z = __builtin_amdgcn_mfma_f32_16x16x32_bf16(a_s[m], bfr[nf][0], z, 0, 0, 0);
            z = __builtin_amdgcn_mfma_f32_16x16x32_bf16(a_c[m], bfr[nf][1], z, 0, 0, 0);
            acc[m][nf] = z;
        }

    // ---- epilogue: + bias, relu, store ----
    const float* bn = bias + n * 64;
    float bv[4];
    #pragma unroll
    for (int nf = 0; nf < 4; ++nf) bv[nf] = bn[nf * 16 + lr];

    #pragma unroll
    for (int m = 0; m < 2; ++m)
        #pragma unroll
        for (int nf = 0; nf < 4; ++nf) {
            int col = nf * 16 + lr;
            #pragma unroll
            for (int r = 0; r < 4; ++r) {
                int row = b0 + w * 32 + m * 16 + lg * 4 + r;
                float v = acc[m][nf][r] + bv[nf];
                out[(size_t)row * 16384 + n * 64 + col] = fmaxf(v, 0.0f);
            }
        }
}

extern "C" void kernel_launch(void* const* d_in, const int* in_sizes, int n_in,
                              void* d_out, int out_size, void* d_ws, size_t ws_size,
                              hipStream_t stream) {
    const float* x    = (const float*)d_in[0];
    const float* coef = (const float*)d_in[1];
    const float* wgt  = (const float*)d_in[2];
    const float* bias = (const float*)d_in[3];
    float* out = (float*)d_out;

    dim3 grid(256 * (8192 / BM));   // 16384 blocks: token index fastest
    dim3 block(256);
    hipLaunchKernelGGL(pe_mfma_kernel, grid, block, 0, stream,
                       x, coef, wgt, bias, out);
}